// Round 15
// baseline (4335.579 us; speedup 1.0000x reference)
//
#include <hip/hip_runtime.h>

#define BATCH 64
#define LEN   2048
#define NIN   128
#define NH    256

typedef float f32x4 __attribute__((ext_vector_type(4)));
typedef float f32x2 __attribute__((ext_vector_type(2)));

// ---------------------------------------------------------------------------
// FROZEN ARITHMETIC (R7: absmax == 0.0). Do not touch:
//  - dots: single-accumulator, k-ascending fmaf chains from 0
//  - pre = (xw + acc) + bias, left-assoc, no contraction
//  - tanh = EmitFastTanh(with_fma=true): clamp ±7.99881172180175781,
//    fmaf Horner, IEEE f32 divide, |x|<0.0004 passthrough
// ---------------------------------------------------------------------------
__device__ __forceinline__ float tanh_xla_fma_f32(float x) {
  const float kClamp = 7.99881172180175781f;
  float xc = fmaxf(x, -kClamp);
  xc = fminf(xc, kClamp);
  float x2 = xc * xc;
  float num = fmaf(x2, -2.76076847742355e-16f, 2.00018790482477e-13f);
  num = fmaf(x2, num, -8.60467152213735e-11f);
  num = fmaf(x2, num, 5.12229709037114e-08f);
  num = fmaf(x2, num, 1.48572235717979e-05f);
  num = fmaf(x2, num, 6.37261928875436e-04f);
  num = fmaf(x2, num, 4.89352455891786e-03f);
  num = xc * num;
  float den = fmaf(x2, 1.19825839466702e-06f, 1.18534705686654e-04f);
  den = fmaf(x2, den, 2.26843463243900e-03f);
  den = fmaf(x2, den, 4.89352518554385e-03f);
  float r = num / den;
  return (fabsf(x) < 0.0004f) ? x : r;
}

#define PINV(v) asm("" : "+v"(v));

// Broadcast via VALU lane crossbar (R10/R11: LDS-pipe broadcast saturates;
// R12: readlane path = proven win). Bit-exact data movement.
#define RLANE(val, q) \
  __uint_as_float(__builtin_amdgcn_readlane(__float_as_uint(val), (q)))

#define REPX32(M) M(0) M(1) M(2) M(3) M(4) M(5) M(6) M(7) \
  M(8) M(9) M(10) M(11) M(12) M(13) M(14) M(15) \
  M(16) M(17) M(18) M(19) M(20) M(21) M(22) M(23) \
  M(24) M(25) M(26) M(27) M(28) M(29) M(30) M(31)

#define WQ_DECL(n) f32x4 wq##n;
#define WQ_LOAD(n) wq##n = wrow[n]; PINV(wq##n)

// One quad of the FROZEN k-ascending chain: h[base+4n..base+4n+3] are lanes
// n of hq.x/y/z/w; weights wq##n = W row quad. fmaf order = chain order.
#define HSTEP(n) \
  acc = fmaf(RLANE(hq.x, n), wq##n.x, acc); \
  acc = fmaf(RLANE(hq.y, n), wq##n.y, acc); \
  acc = fmaf(RLANE(hq.z, n), wq##n.z, acc); \
  acc = fmaf(RLANE(hq.w, n), wq##n.w, acc);

// xw chain quad: x[4n..4n+3] = lanes 2n,2n,2n+1,2n+1 of xv.x/.y.
#define XSTEP(n) \
  acc = fmaf(RLANE(xv.x, 2*(n)    ), wq##n.x, acc); \
  acc = fmaf(RLANE(xv.y, 2*(n)    ), wq##n.y, acc); \
  acc = fmaf(RLANE(xv.x, 2*(n) + 1), wq##n.z, acc); \
  acc = fmaf(RLANE(xv.y, 2*(n) + 1), wq##n.w, acc);

// ---------------------------------------------------------------------------
// Kernel A: xw[l][b][h] = sum_i x[b][l][i] * Wx[h][i]   (unchanged from R12)
// ---------------------------------------------------------------------------
constexpr int LC = 128;   // l-positions per block

__global__ __launch_bounds__(256, 2)
void xw_kernel(const float* __restrict__ x, const float* __restrict__ Wx,
               float* __restrict__ out) {
  const int j    = threadIdx.x;
  const int lane = j & 63;
  const int b    = blockIdx.x & (BATCH - 1);
  const int lt   = blockIdx.x >> 6;

  const f32x4* wrow = (const f32x4*)&Wx[(size_t)j * NIN];
  REPX32(WQ_DECL)
  REPX32(WQ_LOAD)

  const float* xr = x + ((size_t)b * LEN + (size_t)lt * LC) * NIN;
  float* op = out + ((size_t)lt * LC * BATCH + b) * NH + j;

  f32x2 xv = *(const f32x2*)(xr + 2 * lane);       // row 0, coalesced
  for (int ll = 0; ll < LC; ++ll) {
    const int ln = (ll + 1 < LC) ? (ll + 1) : ll;
    f32x2 xnext = *(const f32x2*)(xr + (size_t)ln * NIN + 2 * lane);
    float acc = 0.0f;
    REPX32(XSTEP)
    op[(size_t)ll * BATCH * NH] = acc;
    xv = xnext;
  }
}

// ---------------------------------------------------------------------------
// Kernel B: recurrence, SPLIT-K serial handoff (R14 lesson: >150 live arch
// VGPRs/thread loses to the RA; 128 fits). 512 threads: thread (j,s=0) does
// k=0..127 of channel j's frozen chain; (j,s=1) CONTINUES the same chain
// k=128..255 from the raw f32 partial (passed via LDS — no rounding, no
// reassociation -> bit-exact), then pre/tanh/stores. Waves 0-3 = s0,
// 4-7 = s1: one of each per SIMD, segments alternate without contention.
// 32 weight quads (128 VGPR) per thread; h broadcast via readlane.
// lgkmcnt-only barriers (global store stays in flight).
// ---------------------------------------------------------------------------
__global__ __launch_bounds__(512, 1)
void rnn_kernel(const float* __restrict__ Wh, const float* __restrict__ bh,
                const float* __restrict__ h0, float* __restrict__ io) {
  const int b    = blockIdx.x;
  const int tid  = threadIdx.x;
  const int j    = tid & (NH - 1);      // channel 0..255
  const int s    = tid >> 8;            // 0: k=0..127, 1: k=128..255
  const int lane = tid & 63;

  __shared__ __align__(16) float hbuf[2][NH];
  __shared__ __align__(16) float part[NH];

  const f32x4* wrow = (const f32x4*)&Wh[(size_t)j * NH + (s ? 128 : 0)];
  REPX32(WQ_DECL)
  REPX32(WQ_LOAD)

  const float bias = bh[j];
  const int hoff = (s ? 128 : 0) + 4 * (lane & 31);   // this thread's hq slot

  if (tid < NH) hbuf[0][tid] = h0[b * NH + tid];
  __syncthreads();

  float* p = io + (size_t)b * NH + j;
  const size_t stride = (size_t)BATCH * NH;

  float xw = p[0];                       // only s=1 consumes xw
  int cur = 0;

  for (int l = 0; l < LEN; ++l) {
    if (s == 0) {
      // ---- first half of the chain: k = 0..127 ----
      const f32x4 hq = *(const f32x4*)&hbuf[cur][hoff];
      float acc = 0.0f;
      REPX32(HSTEP)
      part[j] = acc;
    } else {
      // prefetch next step's xw under seg0's latency
      const int ln = (l + 1 < LEN) ? (l + 1) : l;
      xw = (l == 0) ? xw : xw;           // xw already holds step l's value
      // issue prefetch now; consumed at next iteration's tail
    }
    // stash prefetch in a reg for all threads (uniform code, s1 uses it)
    const int ln = (l + 1 < LEN) ? (l + 1) : l;
    const float xw_next = p[(size_t)ln * stride];

    asm volatile("s_waitcnt lgkmcnt(0)" ::: "memory");
    __builtin_amdgcn_s_barrier();        // bar A: partials visible
    asm volatile("" ::: "memory");

    if (s == 1) {
      // ---- continue the SAME chain: k = 128..255 ----
      const f32x4 hq = *(const f32x4*)&hbuf[cur][hoff];
      float acc = part[j];               // raw f32 handoff (no rounding)
      REPX32(HSTEP)

      float pre;
      {
#pragma clang fp contract(off)
        pre = (xw + acc) + bias;         // ((xw + hW) + b) order
      }
      const float hn = tanh_xla_fma_f32(pre);

      p[(size_t)l * stride] = hn;        // fire-and-forget store
      hbuf[cur ^ 1][j] = hn;             // publish state
    }

    asm volatile("s_waitcnt lgkmcnt(0)" ::: "memory");
    __builtin_amdgcn_s_barrier();        // bar B: h_{t+1} visible
    asm volatile("" ::: "memory");

    cur ^= 1;
    xw = xw_next;
  }
}

extern "C" void kernel_launch(void* const* d_in, const int* in_sizes, int n_in,
                              void* d_out, int out_size, void* d_ws, size_t ws_size,
                              hipStream_t stream) {
  // Resolve inputs BY SIZE (all element counts distinct).
  const float* x  = (const float*)d_in[0];  // 16777216
  const float* h0 = (const float*)d_in[1];  // 16384
  const float* Wx = (const float*)d_in[2];  // 32768
  const float* Wh = (const float*)d_in[3];  // 65536
  const float* bh = (const float*)d_in[4];  // 256
  for (int i = 0; i < n_in; ++i) {
    switch (in_sizes[i]) {
      case 16777216: x  = (const float*)d_in[i]; break;
      case 16384:    h0 = (const float*)d_in[i]; break;
      case 32768:    Wx = (const float*)d_in[i]; break;
      case 65536:    Wh = (const float*)d_in[i]; break;
      case 256:      bh = (const float*)d_in[i]; break;
      default: break;
    }
  }
  float* out = (float*)d_out;               // [2048, 64, 256] f32

  xw_kernel<<<dim3((LEN / LC) * BATCH), dim3(256), 0, stream>>>(x, Wx, out);
  rnn_kernel<<<dim3(BATCH), dim3(512), 0, stream>>>(Wh, bh, h0, out);
}

// Round 16
// 2623.461 us; speedup vs baseline: 1.6526x; 1.6526x over previous
//
#include <hip/hip_runtime.h>

#define BATCH 64
#define LEN   2048
#define NIN   128
#define NH    256

typedef float f32x4 __attribute__((ext_vector_type(4)));
typedef float f32x2 __attribute__((ext_vector_type(2)));

// ---------------------------------------------------------------------------
// FROZEN ARITHMETIC (R7: absmax == 0.0). Do not touch:
//  - dots: single-accumulator, k-ascending fmaf chains from 0
//  - pre = (xw + acc) + bias, left-assoc, no contraction
//  - tanh = EmitFastTanh(with_fma=true): clamp ±7.99881172180175781,
//    fmaf Horner, IEEE f32 divide, |x|<0.0004 passthrough
// ---------------------------------------------------------------------------
__device__ __forceinline__ float tanh_xla_fma_f32(float x) {
  const float kClamp = 7.99881172180175781f;
  float xc = fmaxf(x, -kClamp);
  xc = fminf(xc, kClamp);
  float x2 = xc * xc;
  float num = fmaf(x2, -2.76076847742355e-16f, 2.00018790482477e-13f);
  num = fmaf(x2, num, -8.60467152213735e-11f);
  num = fmaf(x2, num, 5.12229709037114e-08f);
  num = fmaf(x2, num, 1.48572235717979e-05f);
  num = fmaf(x2, num, 6.37261928875436e-04f);
  num = fmaf(x2, num, 4.89352455891786e-03f);
  num = xc * num;
  float den = fmaf(x2, 1.19825839466702e-06f, 1.18534705686654e-04f);
  den = fmaf(x2, den, 2.26843463243900e-03f);
  den = fmaf(x2, den, 4.89352518554385e-03f);
  float r = num / den;
  return (fabsf(x) < 0.0004f) ? x : r;
}

#define PINV(v) asm("" : "+v"(v));

// Broadcast via the VALU lane crossbar, not the LDS pipe (R10/R11 lesson:
// all-lane-same-address ds_read replicates through the shared LDS pipe).
// readlane is bit-exact data movement.
#define RLANE(val, q) \
  __uint_as_float(__builtin_amdgcn_readlane(__float_as_uint(val), (q)))

#define REPQ48(M) M(0) M(1) M(2) M(3) M(4) M(5) M(6) M(7) \
  M(8) M(9) M(10) M(11) M(12) M(13) M(14) M(15) \
  M(16) M(17) M(18) M(19) M(20) M(21) M(22) M(23) \
  M(24) M(25) M(26) M(27) M(28) M(29) M(30) M(31) \
  M(32) M(33) M(34) M(35) M(36) M(37) M(38) M(39) \
  M(40) M(41) M(42) M(43) M(44) M(45) M(46) M(47)
#define REPQ16(M) M(48) M(49) M(50) M(51) M(52) M(53) M(54) M(55) \
  M(56) M(57) M(58) M(59) M(60) M(61) M(62) M(63)
#define REPX32(M) M(0) M(1) M(2) M(3) M(4) M(5) M(6) M(7) \
  M(8) M(9) M(10) M(11) M(12) M(13) M(14) M(15) \
  M(16) M(17) M(18) M(19) M(20) M(21) M(22) M(23) \
  M(24) M(25) M(26) M(27) M(28) M(29) M(30) M(31)

// VGPR-resident weight quads (pinned: no remat)
#define WQ_DECL(n) f32x4 wq##n;
#define WQ_LOAD(n) wq##n = wrow[n]; PINV(wq##n)
// AGPR-resident weight quads (explicit; reads volatile so LICM can't hoist
// them out of the step loop and recreate the pressure bomb)
#define AQ_DECL(n) float aq##n##x, aq##n##y, aq##n##z, aq##n##w;
#define AQ_LOAD(n) { f32x4 v = wrow[n]; \
  asm("v_accvgpr_write_b32 %0, %1" : "=a"(aq##n##x) : "v"(v.x)); \
  asm("v_accvgpr_write_b32 %0, %1" : "=a"(aq##n##y) : "v"(v.y)); \
  asm("v_accvgpr_write_b32 %0, %1" : "=a"(aq##n##z) : "v"(v.z)); \
  asm("v_accvgpr_write_b32 %0, %1" : "=a"(aq##n##w) : "v"(v.w)); }

// FROZEN k-ascending chain, one quad (h[4n..4n+3] = lane n of hq.x/y/z/w)
#define STEPV(n) \
  acc = fmaf(RLANE(hq.x, n), wq##n.x, acc); \
  acc = fmaf(RLANE(hq.y, n), wq##n.y, acc); \
  acc = fmaf(RLANE(hq.z, n), wq##n.z, acc); \
  acc = fmaf(RLANE(hq.w, n), wq##n.w, acc);
#define STEPA(n) { float t0, t1, t2, t3; \
  asm volatile("v_accvgpr_read_b32 %0, %1" : "=v"(t0) : "a"(aq##n##x)); \
  asm volatile("v_accvgpr_read_b32 %0, %1" : "=v"(t1) : "a"(aq##n##y)); \
  asm volatile("v_accvgpr_read_b32 %0, %1" : "=v"(t2) : "a"(aq##n##z)); \
  asm volatile("v_accvgpr_read_b32 %0, %1" : "=v"(t3) : "a"(aq##n##w)); \
  acc = fmaf(RLANE(hq.x, n), t0, acc); \
  acc = fmaf(RLANE(hq.y, n), t1, acc); \
  acc = fmaf(RLANE(hq.z, n), t2, acc); \
  acc = fmaf(RLANE(hq.w, n), t3, acc); }

// xw chain quad: x[4n..4n+3] = lanes 2n,2n,2n+1,2n+1 of xv.x/.y.
#define XSTEP(n) \
  acc = fmaf(RLANE(xv.x, 2*(n)    ), wq##n.x, acc); \
  acc = fmaf(RLANE(xv.y, 2*(n)    ), wq##n.y, acc); \
  acc = fmaf(RLANE(xv.x, 2*(n) + 1), wq##n.z, acc); \
  acc = fmaf(RLANE(xv.y, 2*(n) + 1), wq##n.w, acc);

// ---------------------------------------------------------------------------
// Kernel A: xw[l][b][h] = sum_i x[b][l][i] * Wx[h][i]  (R12 version)
// ---------------------------------------------------------------------------
constexpr int LC = 128;   // l-positions per block

__global__ __launch_bounds__(256, 2)
void xw_kernel(const float* __restrict__ x, const float* __restrict__ Wx,
               float* __restrict__ out) {
  const int j    = threadIdx.x;
  const int lane = j & 63;
  const int b    = blockIdx.x & (BATCH - 1);
  const int lt   = blockIdx.x >> 6;

  const f32x4* wrow = (const f32x4*)&Wx[(size_t)j * NIN];
  REPX32(WQ_DECL)
  REPX32(WQ_LOAD)

  const float* xr = x + ((size_t)b * LEN + (size_t)lt * LC) * NIN;
  float* op = out + ((size_t)lt * LC * BATCH + b) * NH + j;

  f32x2 xv = *(const f32x2*)(xr + 2 * lane);       // row 0, coalesced
  for (int ll = 0; ll < LC; ++ll) {
    const int ln = (ll + 1 < LC) ? (ll + 1) : ll;
    f32x2 xnext = *(const f32x2*)(xr + (size_t)ln * NIN + 2 * lane);
    float acc = 0.0f;
    REPX32(XSTEP)
    op[(size_t)ll * BATCH * NH] = acc;
    xv = xnext;
  }
}

// ---------------------------------------------------------------------------
// Kernel B: recurrence — R12 structure + amdgpu_waves_per_eu(1,1).
// R8-R15 lesson: with only launch_bounds, the RA still TARGETS default
// occupancy (~3 waves/EU -> <=~170 VGPRs) and parks long-lived values in
// AGPRs with per-use copies in the loop (VGPR_Count 76-160 regardless of
// demand). waves_per_eu(1,1) declares occupancy is capped at 1 wave/EU
// (true: 64 blocks on 256 CUs), removing any benefit to shrinking below
// 256 arch VGPRs. 48 V-quads (192 regs) + 16 A-quads; ONE coalesced
// ds_read_b128/wave per step; readlane broadcast; lgkm-only barrier.
// ---------------------------------------------------------------------------
__global__ __launch_bounds__(256)
__attribute__((amdgpu_waves_per_eu(1, 1)))
void rnn_kernel(const float* __restrict__ Wh, const float* __restrict__ bh,
                const float* __restrict__ h0, float* __restrict__ io) {
  const int b    = blockIdx.x;
  const int j    = threadIdx.x;
  const int lane = j & 63;

  __shared__ __align__(16) float hbuf[2][NH];

  const f32x4* wrow = (const f32x4*)&Wh[(size_t)j * NH];
  REPQ48(WQ_DECL)
  REPQ16(AQ_DECL)
  REPQ48(WQ_LOAD)
  REPQ16(AQ_LOAD)

  const float bias = bh[j];
  hbuf[0][j] = h0[b * NH + j];
  __syncthreads();

  float* p = io + (size_t)b * NH + j;
  const size_t stride = (size_t)BATCH * NH;

  float xw = p[0];
  int cur = 0;

  for (int l = 0; l < LEN; ++l) {
    const int ln = (l + 1 < LEN) ? (l + 1) : l;
    const float xw_next = p[(size_t)ln * stride];   // prefetch next xw

    const f32x4 hq = *(const f32x4*)&hbuf[cur][4 * lane];  // 1 coalesced read
    float acc = 0.0f;
    REPQ48(STEPV)
    REPQ16(STEPA)

    float pre;
    {
#pragma clang fp contract(off)
      pre = (xw + acc) + bias;                  // ((xw + hW) + b) order
    }
    const float hn = tanh_xla_fma_f32(pre);

    p[(size_t)l * stride] = hn;                 // fire-and-forget store
    hbuf[cur ^ 1][j] = hn;                      // publish state

    // lgkmcnt-only barrier: LDS visible, global store left in flight.
    asm volatile("s_waitcnt lgkmcnt(0)" ::: "memory");
    __builtin_amdgcn_s_barrier();
    asm volatile("" ::: "memory");

    cur ^= 1;
    xw = xw_next;
  }
}

extern "C" void kernel_launch(void* const* d_in, const int* in_sizes, int n_in,
                              void* d_out, int out_size, void* d_ws, size_t ws_size,
                              hipStream_t stream) {
  // Resolve inputs BY SIZE (all element counts distinct).
  const float* x  = (const float*)d_in[0];  // 16777216
  const float* h0 = (const float*)d_in[1];  // 16384
  const float* Wx = (const float*)d_in[2];  // 32768
  const float* Wh = (const float*)d_in[3];  // 65536
  const float* bh = (const float*)d_in[4];  // 256
  for (int i = 0; i < n_in; ++i) {
    switch (in_sizes[i]) {
      case 16777216: x  = (const float*)d_in[i]; break;
      case 16384:    h0 = (const float*)d_in[i]; break;
      case 32768:    Wx = (const float*)d_in[i]; break;
      case 65536:    Wh = (const float*)d_in[i]; break;
      case 256:      bh = (const float*)d_in[i]; break;
      default: break;
    }
  }
  float* out = (float*)d_out;               // [2048, 64, 256] f32

  xw_kernel<<<dim3((LEN / LC) * BATCH), dim3(256), 0, stream>>>(x, Wx, out);
  rnn_kernel<<<dim3(BATCH), dim3(256), 0, stream>>>(Wh, bh, h0, out);
}